// Round 5
// baseline (215.584 us; speedup 1.0000x reference)
//
#include <hip/hip_runtime.h>
#include <hip/hip_bf16.h>
#include <stdint.h>

typedef unsigned short u16;
typedef unsigned int u32;
typedef __bf16 bf16x8 __attribute__((ext_vector_type(8)));
typedef _Float16 f16x8 __attribute__((ext_vector_type(8)));
typedef _Float16 f16x4 __attribute__((ext_vector_type(4)));
typedef float f32x4 __attribute__((ext_vector_type(4)));
typedef float f32x16 __attribute__((ext_vector_type(16)));
typedef unsigned short u16x4 __attribute__((ext_vector_type(4)));
typedef unsigned int u32x4 __attribute__((ext_vector_type(4)));

#define SEQ     1024
#define DIM     768
#define NH      12
#define QKV_LD  2304
#define LOG2E   1.4426950408889634f
#define C1      0.18033688f   /* 0.125 * log2(e) */

__device__ __forceinline__ float bf2f(u16 u) {
    union { unsigned v; float f; } x; x.v = ((unsigned)u) << 16; return x.f;
}
__device__ __forceinline__ u16 f2bf(float f) {
    union { float f; unsigned v; } x; x.f = f;
    unsigned r = (x.v + 0x7FFFu + ((x.v >> 16) & 1u)) >> 16;
    return (u16)r;
}
__device__ __forceinline__ void store_out(u16* p, float v)  { *p = f2bf(v); }
__device__ __forceinline__ void store_out(float* p, float v){ *p = v; }

// async global->LDS, 16B per lane. HW semantics: LDS dest = wave base + lane*16.
__device__ __forceinline__ void async16(void* lds, const void* g) {
    __builtin_amdgcn_global_load_lds(
        (const __attribute__((address_space(1))) unsigned*)(uintptr_t)g,
        (__attribute__((address_space(3))) unsigned*)(unsigned)(uintptr_t)lds,
        16, 0, 0);
}

// ---------------- fp32 -> bf16 convert (x) ----------------
__global__ __launch_bounds__(256) void cvt_k(const float* __restrict__ in,
                                             u16* __restrict__ out) {
    int i = (blockIdx.x * 256 + threadIdx.x) * 4;
    float4 v = *(const float4*)(in + i);
    u16x4 o = { f2bf(v.x), f2bf(v.y), f2bf(v.z), f2bf(v.w) };
    *(u16x4*)(out + i) = o;
}

// ---------------- transpose + convert (fp32 weights -> bf16 B^T) ----------------
__global__ __launch_bounds__(256) void transpose_k(const float* __restrict__ in,
                                                   u16* __restrict__ out,
                                                   int R, int C) {
    __shared__ __align__(16) float t[32][33];
    int c0 = blockIdx.x * 32, r0 = blockIdx.y * 32;
    int tx = threadIdx.x & 31, ty = threadIdx.x >> 5;
#pragma unroll
    for (int i = 0; i < 32; i += 8)
        t[ty + i][tx] = in[(size_t)(r0 + ty + i) * C + c0 + tx];
    __syncthreads();
#pragma unroll
    for (int i = 0; i < 32; i += 8)
        out[(size_t)(c0 + ty + i) * R + r0 + tx] = f2bf(t[tx][ty + i]);
}

// -------- V transpose: ws_qkv V-slice (bf16) -> vT[b][h][dh][seq] (f16) --------
__global__ __launch_bounds__(256) void vt_k(const u16* __restrict__ qkv,
                                            _Float16* __restrict__ vT) {
    __shared__ __align__(16) u16 t[32][33];
    int bh = blockIdx.z;
    int b = bh / 12, h = bh % 12;
    int key0 = blockIdx.x * 32, dh0 = blockIdx.y * 32;
    int tx = threadIdx.x & 31, ty = threadIdx.x >> 5;
#pragma unroll
    for (int i = 0; i < 32; i += 8)
        t[ty + i][tx] = qkv[(size_t)(b * SEQ + key0 + ty + i) * QKV_LD +
                            1536 + h * 64 + dh0 + tx];
    __syncthreads();
#pragma unroll
    for (int i = 0; i < 32; i += 8)
        vT[(size_t)(bh * 64 + dh0 + ty + i) * SEQ + key0 + tx] =
            (_Float16)bf2f(t[tx][ty + i]);
}

// ------- GEMM: C[M,N] = A[M,K]*Bt[N,K]^T (+fp32 bias), bf16, BK=64 ------------
template <int HAS_BIAS, typename OUT_T>
__global__ __launch_bounds__(256) void gemm_bt(const u16* __restrict__ A,
                                               const u16* __restrict__ Bt,
                                               const float* __restrict__ bias,
                                               OUT_T* __restrict__ C,
                                               int M, int N, int K) {
    __shared__ __align__(16) u16 sA[128 * 64];
    __shared__ __align__(16) u16 sB[128 * 64];
    const int tid = threadIdx.x;
    const int lane = tid & 63;
    const int quad = lane >> 4, l16 = lane & 15;
    const int wave = tid >> 6;
    const int m0 = blockIdx.x * 128, n0 = blockIdx.y * 128;
    const int wm = (wave >> 1) * 64, wn = (wave & 1) * 64;

    const int co0 = (quad ^ (l16 & 7)) * 8;
    f32x4 acc[4][4] = {};

    for (int k0 = 0; k0 < K; k0 += 64) {
        __syncthreads();
#pragma unroll
        for (int rep = 0; rep < 4; ++rep) {
            int i = rep * 256 + tid;
            int row = i >> 3;
            int c = (i & 7) ^ (row & 7);
            async16(&sA[i * 8], A + (size_t)(m0 + row) * K + k0 + c * 8);
            async16(&sB[i * 8], Bt + (size_t)(n0 + row) * K + k0 + c * 8);
        }
        __syncthreads();

#pragma unroll
        for (int ks = 0; ks < 2; ++ks) {
            const int co = co0 ^ (ks * 32);
            bf16x8 af[4], bfr[4];
#pragma unroll
            for (int mi = 0; mi < 4; ++mi)
                af[mi] = *(const bf16x8*)&sA[(wm + mi * 16 + l16) * 64 + co];
#pragma unroll
            for (int nj = 0; nj < 4; ++nj)
                bfr[nj] = *(const bf16x8*)&sB[(wn + nj * 16 + l16) * 64 + co];
#pragma unroll
            for (int mi = 0; mi < 4; ++mi)
#pragma unroll
                for (int nj = 0; nj < 4; ++nj)
                    acc[mi][nj] = __builtin_amdgcn_mfma_f32_16x16x32_bf16(
                        af[mi], bfr[nj], acc[mi][nj], 0, 0, 0);
        }
    }

#pragma unroll
    for (int mi = 0; mi < 4; ++mi) {
#pragma unroll
        for (int nj = 0; nj < 4; ++nj) {
            int col = n0 + wn + nj * 16 + l16;
            float bv = HAS_BIAS ? bias[col] : 0.0f;
#pragma unroll
            for (int r = 0; r < 4; ++r) {
                int row = m0 + wm + mi * 16 + quad * 4 + r;
                store_out(&C[(size_t)row * N + col], acc[mi][nj][r] + bv);
            }
        }
    }
}

// ------------- fused attention v10: LDS-traffic diet (V from L2, f16 LUT) -------
// v8/v9 diagnosis: LDS pipe saturated (~24KB reads/wave/tile: K 8KB + V 8KB +
// LUT b32 8KB -> ~29us of LDS occupancy in a 45us kernel; MfmaUtil/VALUBusy both
// low; v9's MFMA reorder changed nothing). v10, serial v8 flow (no cross-barrier
// state -> no spills):
//  * V read DIRECTLY from global vT (L2-resident, 128KB/bh reused by 8 q-blocks):
//    PV A-frag = 16B/lane at row dh. Moves 8KB/wave/tile from LDS to the idle
//    VMEM pipe; V loads issued at tile start, QK+exp (~800cy) hides L2 latency.
//    Deletes sV staging; LDS 40KB -> 33KB.
//  * bias LUT as f16, 4 copies shifted by j (reversed order): lane picks copy
//    (-l31)&3 so the 4 consecutive values per group are ONE aligned ds_read_b64.
//    8KB/32 instrs -> 4KB/8 instrs per wave/tile; kills the b32 2-way conflicts.
// LDS reads/wave/tile: 24KB -> 12KB. Numerics: identical path except bias
// rounded to f16 (|bias|<0.15 -> <1e-4 exponent err, negligible).
__global__ __launch_bounds__(256, 3) void attn_k(const u16* __restrict__ qkv,
                                                 const _Float16* __restrict__ vT,
                                                 const float* __restrict__ bias_table,
                                                 u16* __restrict__ out) {
    __shared__ __align__(16) u16 sK[2][64 * 64];        // [key][dh], chunk-swizzled
    __shared__ __align__(16) _Float16 sLutH[4 * 2052];  // f16 LUT, 4 shifted copies

    const int tid = threadIdx.x;
    const int wave = tid >> 6, lane = tid & 63;
    const int l31 = lane & 31, hi = lane >> 5;
    const int bh = blockIdx.x;
    const int b = bh / NH, h = bh % NH;
    const int q0 = blockIdx.y * 128, wq = wave * 32;

    // LUT copies: sLutH[j][u] = f16(LOG2E * bias[z]), z = 2047 - u - j (reversed)
#pragma unroll
    for (int j = 0; j < 4; ++j)
        for (int u = tid; u < 2052; u += 256) {
            int z = 2047 - u - j;
            float v = 0.f;
            if (z >= 0 && z <= 2046)
                v = LOG2E * bias_table[h * 2047 + (z <= 1023 ? 1023 - z : z)];
            sLutH[j * 2052 + u] = (_Float16)v;
        }

    // Q fragments: B-operand of 32x32x16_bf16 (col=q=l31, k = ks*16 + hi*8 + j)
    bf16x8 qf[4];
#pragma unroll
    for (int ks = 0; ks < 4; ++ks)
        qf[ks] = *(const bf16x8*)(qkv +
            (size_t)(b * SEQ + q0 + wq + l31) * QKV_LD + h * 64 + ks * 16 + hi * 8);

    // K staging addresses
    const u16* kgp[2];
    int lds_i[2];
#pragma unroll
    for (int rep = 0; rep < 2; ++rep) {
        int i = rep * 256 + wave * 64 + lane;
        int row = i >> 3;
        int c = (i & 7) ^ (row & 7);
        kgp[rep] = qkv + (size_t)(b * SEQ + row) * QKV_LD + 768 + h * 64 + c * 8;
        lds_i[rep] = i * 8;
    }

    // V base: PV A-frag row = dh = dt*32 + l31, key = kt*64 + kg*16 + hi*8 + j
    const _Float16* vb0 = vT + (size_t)(bh * 64 + l31) * SEQ + hi * 8;

    // LUT addressing: element r of b64 at (copy r0)*2052 - r0 + ub + 8g equals
    // lut[ibt - 8g - r]; ub = 2047 - ibt; alignment: (ub - r0) % 4 == 0.
    const int r0 = (-l31) & 3;
    const _Float16* lutp = sLutH + (r0 * 2052 - r0);
    const int ub0 = 1024 - q0 - wq - l31 + hi * 4;
    const int l7 = l31 & 7;
    const int hi4 = hi * 4;

    // prologue: stage K tile 0 into buffer 0
#pragma unroll
    for (int rep = 0; rep < 2; ++rep) {
        async16(&sK[0][lds_i[rep]], kgp[rep]);
        kgp[rep] += (size_t)64 * QKV_LD;
    }
    __syncthreads();   // drains async, publishes LUT

    f32x16 o[2] = {};    // O^T: row dh = dt*32 + (reg&3)+8*(reg>>2)+4*hi, col q = l31
    f32x16 osum = {};    // all rows identical = sum_key P[key][q]
    const u32x4 onebits = { 0x3C003C00u, 0x3C003C00u, 0x3C003C00u, 0x3C003C00u };
    const f16x8 ones = __builtin_bit_cast(f16x8, onebits);

    for (int kt = 0; kt < SEQ / 64; ++kt) {
        const int cur = kt & 1;
        if (kt + 1 < SEQ / 64) {
#pragma unroll
            for (int rep = 0; rep < 2; ++rep) {
                async16(&sK[cur ^ 1][lds_i[rep]], kgp[rep]);
                kgp[rep] += (size_t)64 * QKV_LD;
            }
        }

        // V(kt) -> regs via global/L2 (issued early; consumed after QK+exp)
        f16x8 vf[8];
#pragma unroll
        for (int dt = 0; dt < 2; ++dt)
#pragma unroll
            for (int kg = 0; kg < 4; ++kg)
                vf[dt * 4 + kg] =
                    *(const f16x8*)(vb0 + (size_t)dt * 32 * SEQ + kt * 64 + kg * 16);

        const u16* sKc = sK[cur];

        // ---- S^T = K*Q^T (2 key-tiles) ----
        f32x16 sAcc[2];
#pragma unroll
        for (int t = 0; t < 2; ++t) {
            const u16* kr = sKc + (t * 32 + l31) * 64;
            f32x16 s = {};
#pragma unroll
            for (int ks = 0; ks < 4; ++ks) {
                int slot = (2 * ks + hi) ^ l7;
                bf16x8 af = *(const bf16x8*)(kr + slot * 8);
                s = __builtin_amdgcn_mfma_f32_32x32x16_bf16(af, qf[ks], s, 0, 0, 0);
            }
            sAcc[t] = s;
        }

        // ---- exp2 -> pack f16 -> permlane swap (P B-frags) ----
        f16x8 pf[4];
#pragma unroll
        for (int t = 0; t < 2; ++t) {
            const int ub = ub0 + kt * 64 + t * 32;
            u32 wlo[4], whi[4];
#pragma unroll
            for (int g = 0; g < 4; ++g) {
                f16x4 bw4 = *(const f16x4*)(lutp + ub + 8 * g);
                float p0 = __builtin_amdgcn_exp2f(sAcc[t][4 * g + 0] * C1 + (float)bw4[0]);
                float p1 = __builtin_amdgcn_exp2f(sAcc[t][4 * g + 1] * C1 + (float)bw4[1]);
                float p2 = __builtin_amdgcn_exp2f(sAcc[t][4 * g + 2] * C1 + (float)bw4[2]);
                float p3 = __builtin_amdgcn_exp2f(sAcc[t][4 * g + 3] * C1 + (float)bw4[3]);
                wlo[g] = __builtin_bit_cast(u32, __builtin_amdgcn_cvt_pkrtz(p0, p1));
                whi[g] = __builtin_bit_cast(u32, __builtin_amdgcn_cvt_pkrtz(p2, p3));
            }
#pragma unroll
            for (int c = 0; c < 2; ++c) {
                auto rlo = __builtin_amdgcn_permlane32_swap(
                    wlo[2 * c], wlo[2 * c + 1], false, false);
                auto rhi = __builtin_amdgcn_permlane32_swap(
                    whi[2 * c], whi[2 * c + 1], false, false);
                u32x4 fw = { rlo[0], rhi[0], rlo[1], rhi[1] };   // W0,W1,W2,W3
                pf[t * 2 + c] = __builtin_bit_cast(f16x8, fw);
            }
        }

        // ---- osum += ones x P ; O^T += V-frag x P-frag ----
        __builtin_amdgcn_s_setprio(1);
#pragma unroll
        for (int kg = 0; kg < 4; ++kg)
            osum = __builtin_amdgcn_mfma_f32_32x32x16_f16(ones, pf[kg], osum, 0, 0, 0);
#pragma unroll
        for (int dt = 0; dt < 2; ++dt)
#pragma unroll
            for (int kg = 0; kg < 4; ++kg)
                o[dt] = __builtin_amdgcn_mfma_f32_32x32x16_f16(
                    vf[dt * 4 + kg], pf[kg], o[dt], 0, 0, 0);
        __builtin_amdgcn_s_setprio(0);

        __syncthreads();   // all waves done with sK[cur]; prefetch landed
    }

    // epilogue: lane q = q0+wq+l31; dh = dt*32 + 8g + 4hi + m
    float inv = __builtin_amdgcn_rcpf(osum[0]);
    size_t rowbase = (size_t)(b * SEQ + q0 + wq + l31) * DIM + h * 64 + hi4;
#pragma unroll
    for (int dt = 0; dt < 2; ++dt) {
#pragma unroll
        for (int g = 0; g < 4; ++g) {
            u16x4 pk = { f2bf(o[dt][4 * g + 0] * inv), f2bf(o[dt][4 * g + 1] * inv),
                         f2bf(o[dt][4 * g + 2] * inv), f2bf(o[dt][4 * g + 3] * inv) };
            *(u16x4*)&out[rowbase + dt * 32 + 8 * g] = pk;
        }
    }
}

extern "C" void kernel_launch(void* const* d_in, const int* in_sizes, int n_in,
                              void* d_out, int out_size, void* d_ws, size_t ws_size,
                              hipStream_t stream) {
    const float* x          = (const float*)d_in[0];  // (8,1024,768) fp32
    const float* w_qkv      = (const float*)d_in[1];  // (768,2304) fp32
    const float* bias_table = (const float*)d_in[2];  // (12,2047) fp32
    const float* w_out      = (const float*)d_in[3];  // (768,768) fp32
    const float* b_out      = (const float*)d_in[4];  // (768,) fp32
    float* out = (float*)d_out;                       // (8,1024,768) fp32

    char* ws = (char*)d_ws;
    u16* ws_qkv        = (u16*)(ws);                   // 37,748,736 B
    u16* ws_attn       = (u16*)(ws + 37748736);        // 12,582,912 B
    u16* ws_xb         = (u16*)(ws + 50331648);        // 12,582,912 B
    u16* ws_wqkvT      = (u16*)(ws + 62914560);        //  3,538,944 B
    u16* ws_woutT      = (u16*)(ws + 66453504);        //  1,179,648 B
    _Float16* ws_vT    = (_Float16*)(ws + 67633152);   // 12,582,912 B (tot 80.2MB)

    cvt_k<<<8 * 1024 * 768 / 1024, 256, 0, stream>>>(x, ws_xb);
    transpose_k<<<dim3(2304 / 32, 768 / 32), 256, 0, stream>>>(w_qkv, ws_wqkvT, 768, 2304);
    transpose_k<<<dim3(768 / 32, 768 / 32), 256, 0, stream>>>(w_out, ws_woutT, 768, 768);

    // qkv = x @ w_qkv : M=8192, N=2304, K=768
    gemm_bt<0, u16><<<dim3(8192 / 128, 2304 / 128), 256, 0, stream>>>(
        ws_xb, ws_wqkvT, nullptr, ws_qkv, 8192, 2304, 768);

    vt_k<<<dim3(SEQ / 32, 2, 8 * NH), 256, 0, stream>>>(ws_qkv, ws_vT);

    attn_k<<<dim3(8 * NH, SEQ / 128, 1), 256, 0, stream>>>(ws_qkv, ws_vT, bias_table, ws_attn);

    // out = attn @ w_out + b_out : M=8192, N=768, K=768
    gemm_bt<1, float><<<dim3(8192 / 128, 768 / 128), 256, 0, stream>>>(
        ws_attn, ws_woutT, b_out, out, 8192, 768, 768);
}

// Round 6
// 201.583 us; speedup vs baseline: 1.0695x; 1.0695x over previous
//
#include <hip/hip_runtime.h>
#include <hip/hip_bf16.h>
#include <stdint.h>

typedef unsigned short u16;
typedef unsigned int u32;
typedef __bf16 bf16x8 __attribute__((ext_vector_type(8)));
typedef _Float16 f16x8 __attribute__((ext_vector_type(8)));
typedef float f32x4 __attribute__((ext_vector_type(4)));
typedef float f32x16 __attribute__((ext_vector_type(16)));
typedef unsigned short u16x4 __attribute__((ext_vector_type(4)));
typedef unsigned int u32x4 __attribute__((ext_vector_type(4)));

#define SEQ     1024
#define DIM     768
#define NH      12
#define QKV_LD  2304
#define LOG2E   1.4426950408889634f
#define C1      0.18033688f   /* 0.125 * log2(e) */

__device__ __forceinline__ float bf2f(u16 u) {
    union { unsigned v; float f; } x; x.v = ((unsigned)u) << 16; return x.f;
}
__device__ __forceinline__ u16 f2bf(float f) {
    union { float f; unsigned v; } x; x.f = f;
    unsigned r = (x.v + 0x7FFFu + ((x.v >> 16) & 1u)) >> 16;
    return (u16)r;
}
__device__ __forceinline__ void store_out(u16* p, float v)  { *p = f2bf(v); }
__device__ __forceinline__ void store_out(float* p, float v){ *p = v; }

// async global->LDS, 16B per lane. HW semantics: LDS dest = wave base + lane*16.
__device__ __forceinline__ void async16(void* lds, const void* g) {
    __builtin_amdgcn_global_load_lds(
        (const __attribute__((address_space(1))) unsigned*)(uintptr_t)g,
        (__attribute__((address_space(3))) unsigned*)(unsigned)(uintptr_t)lds,
        16, 0, 0);
}

// ---------------- fp32 -> bf16 convert (x) ----------------
__global__ __launch_bounds__(256) void cvt_k(const float* __restrict__ in,
                                             u16* __restrict__ out) {
    int i = (blockIdx.x * 256 + threadIdx.x) * 4;
    float4 v = *(const float4*)(in + i);
    u16x4 o = { f2bf(v.x), f2bf(v.y), f2bf(v.z), f2bf(v.w) };
    *(u16x4*)(out + i) = o;
}

// ---------------- transpose + convert (fp32 weights -> bf16 B^T) ----------------
__global__ __launch_bounds__(256) void transpose_k(const float* __restrict__ in,
                                                   u16* __restrict__ out,
                                                   int R, int C) {
    __shared__ __align__(16) float t[32][33];
    int c0 = blockIdx.x * 32, r0 = blockIdx.y * 32;
    int tx = threadIdx.x & 31, ty = threadIdx.x >> 5;
#pragma unroll
    for (int i = 0; i < 32; i += 8)
        t[ty + i][tx] = in[(size_t)(r0 + ty + i) * C + c0 + tx];
    __syncthreads();
#pragma unroll
    for (int i = 0; i < 32; i += 8)
        out[(size_t)(c0 + ty + i) * R + r0 + tx] = f2bf(t[tx][ty + i]);
}

// -------- V transpose: ws_qkv V-slice (bf16) -> vT[b][h][dh][seq] (f16) --------
__global__ __launch_bounds__(256) void vt_k(const u16* __restrict__ qkv,
                                            _Float16* __restrict__ vT) {
    __shared__ __align__(16) u16 t[32][33];
    int bh = blockIdx.z;
    int b = bh / 12, h = bh % 12;
    int key0 = blockIdx.x * 32, dh0 = blockIdx.y * 32;
    int tx = threadIdx.x & 31, ty = threadIdx.x >> 5;
#pragma unroll
    for (int i = 0; i < 32; i += 8)
        t[ty + i][tx] = qkv[(size_t)(b * SEQ + key0 + ty + i) * QKV_LD +
                            1536 + h * 64 + dh0 + tx];
    __syncthreads();
#pragma unroll
    for (int i = 0; i < 32; i += 8)
        vT[(size_t)(bh * 64 + dh0 + ty + i) * SEQ + key0 + tx] =
            (_Float16)bf2f(t[tx][ty + i]);
}

// ------- GEMM: C[M,N] = A[M,K]*Bt[N,K]^T (+fp32 bias), bf16, BK=64 ------------
// v11: bijective XCD-aware block swizzle (T1) — launches guarantee nwg % 8 == 0,
// so chunk = nwg/8; round-robin-dispatched blocks become contiguous tile chunks
// per XCD -> A/B panel reuse in the per-XCD L2.
template <int HAS_BIAS, typename OUT_T>
__global__ __launch_bounds__(256) void gemm_bt(const u16* __restrict__ A,
                                               const u16* __restrict__ Bt,
                                               const float* __restrict__ bias,
                                               OUT_T* __restrict__ C,
                                               int M, int N, int K) {
    __shared__ __align__(16) u16 sA[128 * 64];
    __shared__ __align__(16) u16 sB[128 * 64];
    const int tid = threadIdx.x;
    const int lane = tid & 63;
    const int quad = lane >> 4, l16 = lane & 15;
    const int wave = tid >> 6;

    const int nwg = gridDim.x * gridDim.y;
    const int wgid = blockIdx.y * gridDim.x + blockIdx.x;
    const int swz = (wgid & 7) * (nwg >> 3) + (wgid >> 3);
    const int m0 = (swz % gridDim.x) * 128, n0 = (swz / gridDim.x) * 128;
    const int wm = (wave >> 1) * 64, wn = (wave & 1) * 64;

    const int co0 = (quad ^ (l16 & 7)) * 8;
    f32x4 acc[4][4] = {};

    for (int k0 = 0; k0 < K; k0 += 64) {
        __syncthreads();
#pragma unroll
        for (int rep = 0; rep < 4; ++rep) {
            int i = rep * 256 + tid;
            int row = i >> 3;
            int c = (i & 7) ^ (row & 7);
            async16(&sA[i * 8], A + (size_t)(m0 + row) * K + k0 + c * 8);
            async16(&sB[i * 8], Bt + (size_t)(n0 + row) * K + k0 + c * 8);
        }
        __syncthreads();

#pragma unroll
        for (int ks = 0; ks < 2; ++ks) {
            const int co = co0 ^ (ks * 32);
            bf16x8 af[4], bfr[4];
#pragma unroll
            for (int mi = 0; mi < 4; ++mi)
                af[mi] = *(const bf16x8*)&sA[(wm + mi * 16 + l16) * 64 + co];
#pragma unroll
            for (int nj = 0; nj < 4; ++nj)
                bfr[nj] = *(const bf16x8*)&sB[(wn + nj * 16 + l16) * 64 + co];
#pragma unroll
            for (int mi = 0; mi < 4; ++mi)
#pragma unroll
                for (int nj = 0; nj < 4; ++nj)
                    acc[mi][nj] = __builtin_amdgcn_mfma_f32_16x16x32_bf16(
                        af[mi], bfr[nj], acc[mi][nj], 0, 0, 0);
        }
    }

#pragma unroll
    for (int mi = 0; mi < 4; ++mi) {
#pragma unroll
        for (int nj = 0; nj < 4; ++nj) {
            int col = n0 + wn + nj * 16 + l16;
            float bv = HAS_BIAS ? bias[col] : 0.0f;
#pragma unroll
            for (int r = 0; r < 4; ++r) {
                int row = m0 + wm + mi * 16 + quad * 4 + r;
                store_out(&C[(size_t)row * N + col], acc[mi][nj][r] + bv);
            }
        }
    }
}

// -------- fused attention v11: v8 + counted vmcnt across the barrier (T4) ------
// v8 profile (Mfma 28, VALU 33, occ 23, nothing saturated) = latency-bound.
// The per-tile __syncthreads lowers to s_waitcnt vmcnt(0): each wave waited for
// its OWN next-tile prefetch (L2/HBM, 300-900cy) every tile. v11 replaces it
// with `s_waitcnt vmcnt(4); s_barrier` (m201-verified pattern): only-in-loop
// VMEM is the 4 async16/tile, so vmcnt(4) proves the PREVIOUS tile's loads
// retired (in-order) while this tile's 4 stay in flight across the barrier.
// Everything else is byte-identical to v8 (44.4us, 64 VGPR, no spills).
__global__ __launch_bounds__(256, 3) void attn_k(const u16* __restrict__ qkv,
                                                 const _Float16* __restrict__ vT,
                                                 const float* __restrict__ bias_table,
                                                 u16* __restrict__ out) {
    __shared__ __align__(16) u16 sK[2][64 * 64];       // [key][dh], chunk-swizzled
    __shared__ __align__(16) _Float16 sV[2][64 * 64];  // [dh][key], chunk-swizzled
    __shared__ __align__(16) float sLut[2048];         // fp32 log2e*bias LUT

    const int tid = threadIdx.x;
    const int wave = tid >> 6, lane = tid & 63;
    const int l31 = lane & 31, hi = lane >> 5;
    const int bh = blockIdx.x;
    const int b = bh / NH, h = bh % NH;
    const int q0 = blockIdx.y * 128, wq = wave * 32;

    // bias LUT: lut[z] = log2e * bias[(z<=1023)?1023-z:z], z = 1023 + (i_q - j_key)
    for (int i = tid; i < 2047; i += 256)
        sLut[i] = LOG2E * bias_table[h * 2047 + (i <= 1023 ? 1023 - i : i)];

    // Q fragments: B-operand of 32x32x16_bf16 (col=q=l31, k = ks*16 + hi*8 + j)
    bf16x8 qf[4];
#pragma unroll
    for (int ks = 0; ks < 4; ++ks)
        qf[ks] = *(const bf16x8*)(qkv +
            (size_t)(b * SEQ + q0 + wq + l31) * QKV_LD + h * 64 + ks * 16 + hi * 8);

    // staging addresses
    const u16* kgp[2];
    const _Float16* vgp[2];
    int lds_i[2];
#pragma unroll
    for (int rep = 0; rep < 2; ++rep) {
        int i = rep * 256 + wave * 64 + lane;
        int row = i >> 3;
        int c = (i & 7) ^ (row & 7);
        kgp[rep] = qkv + (size_t)(b * SEQ + row) * QKV_LD + 768 + h * 64 + c * 8;
        vgp[rep] = vT + (size_t)(bh * 64 + row) * SEQ + c * 8;
        lds_i[rep] = i * 8;
    }

    const int ib0 = 1023 + q0 + wq + l31;
    const int hi4 = hi * 4;
    const int l7 = l31 & 7;

    // prologue: stage tile 0 into buffer 0
#pragma unroll
    for (int rep = 0; rep < 2; ++rep) {
        async16(&sK[0][lds_i[rep]], kgp[rep]);
        async16(&sV[0][lds_i[rep]], vgp[rep]);
        kgp[rep] += (size_t)64 * QKV_LD;
        vgp[rep] += 64;
    }
    __syncthreads();   // full drain: tile 0 + LUT published

    f32x16 o[2] = {};    // O^T: row dh = dt*32 + (reg&3)+8*(reg>>2)+4*hi, col q = l31
    f32x16 osum = {};    // all rows identical = sum_key P[key][q]
    const u32x4 onebits = { 0x3C003C00u, 0x3C003C00u, 0x3C003C00u, 0x3C003C00u };
    const f16x8 ones = __builtin_bit_cast(f16x8, onebits);

    for (int kt = 0; kt < SEQ / 64; ++kt) {
        const int cur = kt & 1;
        if (kt + 1 < SEQ / 64) {
            const int nxt = cur ^ 1;
#pragma unroll
            for (int rep = 0; rep < 2; ++rep) {
                async16(&sK[nxt][lds_i[rep]], kgp[rep]);
                async16(&sV[nxt][lds_i[rep]], vgp[rep]);
                kgp[rep] += (size_t)64 * QKV_LD;
                vgp[rep] += 64;
            }
        }
        const u16* sKc = sK[cur];
        const _Float16* sVc = sV[cur];

        // ---- S^T = K*Q^T (2 key-tiles) -> exp -> pack -> permlane swap ----
        f16x8 pfrag[4];   // B-frags for PV, kg = key group of 16
#pragma unroll
        for (int t = 0; t < 2; ++t) {
            const u16* kr = sKc + (t * 32 + l31) * 64;
            f32x16 s = {};
#pragma unroll
            for (int ks = 0; ks < 4; ++ks) {
                int slot = (2 * ks + hi) ^ l7;
                bf16x8 af = *(const bf16x8*)(kr + slot * 8);
                s = __builtin_amdgcn_mfma_f32_32x32x16_bf16(af, qf[ks], s, 0, 0, 0);
            }
            // key = kt*64 + t*32 + m + 8g + 4hi ; z = ib0 - key
            const int ibt = ib0 - kt * 64 - t * 32 - hi4;
            u32 wlo[4], whi[4];
#pragma unroll
            for (int g = 0; g < 4; ++g) {
                const float* bw = &sLut[ibt - 8 * g];
                float p0 = __builtin_amdgcn_exp2f(s[4 * g + 0] * C1 + bw[0]);
                float p1 = __builtin_amdgcn_exp2f(s[4 * g + 1] * C1 + bw[-1]);
                float p2 = __builtin_amdgcn_exp2f(s[4 * g + 2] * C1 + bw[-2]);
                float p3 = __builtin_amdgcn_exp2f(s[4 * g + 3] * C1 + bw[-3]);
                wlo[g] = __builtin_bit_cast(u32, __builtin_amdgcn_cvt_pkrtz(p0, p1));
                whi[g] = __builtin_bit_cast(u32, __builtin_amdgcn_cvt_pkrtz(p2, p3));
            }
            // frag kg=2t+c: W0/W1 = keys 16kg+hi*8+{0..3}, W2/W3 = +4.
            // swap(wlo[2c], wlo[2c+1]): r[0]=W0, r[1]=W2.
#pragma unroll
            for (int c = 0; c < 2; ++c) {
                auto rlo = __builtin_amdgcn_permlane32_swap(
                    wlo[2 * c], wlo[2 * c + 1], false, false);
                auto rhi = __builtin_amdgcn_permlane32_swap(
                    whi[2 * c], whi[2 * c + 1], false, false);
                u32x4 f = { rlo[0], rhi[0], rlo[1], rhi[1] };   // W0,W1,W2,W3
                pfrag[t * 2 + c] = __builtin_bit_cast(f16x8, f);
            }
        }

        // ---- osum += ones x P ; O^T += V^T-frag x P-frag ----
#pragma unroll
        for (int kg = 0; kg < 4; ++kg)
            osum = __builtin_amdgcn_mfma_f32_32x32x16_f16(ones, pfrag[kg], osum, 0, 0, 0);
#pragma unroll
        for (int dt = 0; dt < 2; ++dt) {
            const _Float16* vr = sVc + (dt * 32 + l31) * 64;
#pragma unroll
            for (int kg = 0; kg < 4; ++kg) {
                int slot = (2 * kg + hi) ^ l7;
                f16x8 vf = *(const f16x8*)(vr + slot * 8);
                o[dt] = __builtin_amdgcn_mfma_f32_32x32x16_f16(vf, pfrag[kg], o[dt], 0, 0, 0);
            }
        }

        // counted-vmcnt barrier (T4): wait only for PREVIOUS tile's 4 async16
        // (older than the 4 just issued; in-order retire), keep this tile's 4
        // in flight across the barrier. Never drain to 0 in the loop.
        if (kt + 1 < SEQ / 64) {
            asm volatile("s_waitcnt vmcnt(4)" ::: "memory");
            __builtin_amdgcn_s_barrier();
        }
    }

    // epilogue: lane q = q0+wq+l31; dh = dt*32 + 8g + 4hi + m
    float inv = __builtin_amdgcn_rcpf(osum[0]);
    size_t rowbase = (size_t)(b * SEQ + q0 + wq + l31) * DIM + h * 64 + hi4;
#pragma unroll
    for (int dt = 0; dt < 2; ++dt) {
#pragma unroll
        for (int g = 0; g < 4; ++g) {
            u16x4 pk = { f2bf(o[dt][4 * g + 0] * inv), f2bf(o[dt][4 * g + 1] * inv),
                         f2bf(o[dt][4 * g + 2] * inv), f2bf(o[dt][4 * g + 3] * inv) };
            *(u16x4*)&out[rowbase + dt * 32 + 8 * g] = pk;
        }
    }
}

extern "C" void kernel_launch(void* const* d_in, const int* in_sizes, int n_in,
                              void* d_out, int out_size, void* d_ws, size_t ws_size,
                              hipStream_t stream) {
    const float* x          = (const float*)d_in[0];  // (8,1024,768) fp32
    const float* w_qkv      = (const float*)d_in[1];  // (768,2304) fp32
    const float* bias_table = (const float*)d_in[2];  // (12,2047) fp32
    const float* w_out      = (const float*)d_in[3];  // (768,768) fp32
    const float* b_out      = (const float*)d_in[4];  // (768,) fp32
    float* out = (float*)d_out;                       // (8,1024,768) fp32

    char* ws = (char*)d_ws;
    u16* ws_qkv        = (u16*)(ws);                   // 37,748,736 B
    u16* ws_attn       = (u16*)(ws + 37748736);        // 12,582,912 B
    u16* ws_xb         = (u16*)(ws + 50331648);        // 12,582,912 B
    u16* ws_wqkvT      = (u16*)(ws + 62914560);        //  3,538,944 B
    u16* ws_woutT      = (u16*)(ws + 66453504);        //  1,179,648 B
    _Float16* ws_vT    = (_Float16*)(ws + 67633152);   // 12,582,912 B (tot 80.2MB)

    cvt_k<<<8 * 1024 * 768 / 1024, 256, 0, stream>>>(x, ws_xb);
    transpose_k<<<dim3(2304 / 32, 768 / 32), 256, 0, stream>>>(w_qkv, ws_wqkvT, 768, 2304);
    transpose_k<<<dim3(768 / 32, 768 / 32), 256, 0, stream>>>(w_out, ws_woutT, 768, 768);

    // qkv = x @ w_qkv : M=8192, N=2304, K=768  (nwg = 64*18 = 1152, %8==0)
    gemm_bt<0, u16><<<dim3(8192 / 128, 2304 / 128), 256, 0, stream>>>(
        ws_xb, ws_wqkvT, nullptr, ws_qkv, 8192, 2304, 768);

    vt_k<<<dim3(SEQ / 32, 2, 8 * NH), 256, 0, stream>>>(ws_qkv, ws_vT);

    attn_k<<<dim3(8 * NH, SEQ / 128, 1), 256, 0, stream>>>(ws_qkv, ws_vT, bias_table, ws_attn);

    // out = attn @ w_out + b_out : M=8192, N=768, K=768  (nwg = 64*6 = 384, %8==0)
    gemm_bt<1, float><<<dim3(8192 / 128, 768 / 128), 256, 0, stream>>>(
        ws_attn, ws_woutT, b_out, out, 8192, 768, 768);
}